// Round 1
// baseline (335.852 us; speedup 1.0000x reference)
//
#include <hip/hip_runtime.h>
#include <cmath>

#define TABLE_SZ 16384u
#define NLEV 16

struct ResArr { float r[NLEV]; };

__global__ __launch_bounds__(256) void mrhe_kernel(
    const float* __restrict__ x,
    const float* __restrict__ tables,
    float* __restrict__ out,
    ResArr res, int B)
{
    int i = blockIdx.x * blockDim.x + threadIdx.x;
    if (i >= B) return;

    float px = x[3*(size_t)i+0];
    float py = x[3*(size_t)i+1];
    float pz = x[3*(size_t)i+2];

    // interp weights from UNSCALED position (faithful to reference)
    float wx = px - floorf(px), wy = py - floorf(py), wz = pz - floorf(pz);
    float ax = 1.0f - wx, ay = 1.0f - wy, az = 1.0f - wz;

    // corner order v0..v7: (0,0,0)(1,0,0)(1,1,0)(0,1,0)(0,0,1)(1,0,1)(1,1,1)(0,1,1)
    // product order (x*y)*z to match jnp.prod left-assoc
    float cw0 = (ax*ay)*az;
    float cw1 = (wx*ay)*az;
    float cw2 = (wx*wy)*az;
    float cw3 = (ax*wy)*az;
    float cw4 = (ax*ay)*wz;
    float cw5 = (wx*ay)*wz;
    float cw6 = (wx*wy)*wz;
    float cw7 = (ax*wy)*wz;

    const uint32_t P1 = 2654435761u, P2 = 805459861u;
    const uint32_t m = TABLE_SZ - 1u;

    float o[2*NLEV];

    #pragma unroll
    for (int l = 0; l < NLEV; ++l) {
        float r = res.r[l];
        float sx = r*px, sy = r*py, sz = r*pz;
        // high = ceil (NOT low+1): when sp is exactly integral, high == low
        uint32_t lx = (uint32_t)(int32_t)floorf(sx);
        uint32_t hx = (uint32_t)(int32_t)ceilf(sx);
        uint32_t ly = (uint32_t)(int32_t)floorf(sy);
        uint32_t hy = (uint32_t)(int32_t)ceilf(sy);
        uint32_t lz = (uint32_t)(int32_t)floorf(sz);
        uint32_t hz = (uint32_t)(int32_t)ceilf(sz);
        uint32_t yl = P1*ly, yh = P1*hy;
        uint32_t zl = P2*lz, zh = P2*hz;
        uint32_t h0 = (lx ^ yl ^ zl) & m;
        uint32_t h1 = (hx ^ yl ^ zl) & m;
        uint32_t h2 = (hx ^ yh ^ zl) & m;
        uint32_t h3 = (lx ^ yh ^ zl) & m;
        uint32_t h4 = (lx ^ yl ^ zh) & m;
        uint32_t h5 = (hx ^ yl ^ zh) & m;
        uint32_t h6 = (hx ^ yh ^ zh) & m;
        uint32_t h7 = (lx ^ yh ^ zh) & m;

        const float2* tb = (const float2*)(tables) + (size_t)l * TABLE_SZ;
        float2 f0 = tb[h0]; float2 f1 = tb[h1];
        float2 f2 = tb[h2]; float2 f3 = tb[h3];
        float2 f4 = tb[h4]; float2 f5 = tb[h5];
        float2 f6 = tb[h6]; float2 f7 = tb[h7];

        float a0 = f0.x*cw0;  float a1 = f0.y*cw0;
        a0 += f1.x*cw1;       a1 += f1.y*cw1;
        a0 += f2.x*cw2;       a1 += f2.y*cw2;
        a0 += f3.x*cw3;       a1 += f3.y*cw3;
        a0 += f4.x*cw4;       a1 += f4.y*cw4;
        a0 += f5.x*cw5;       a1 += f5.y*cw5;
        a0 += f6.x*cw6;       a1 += f6.y*cw6;
        a0 += f7.x*cw7;       a1 += f7.y*cw7;

        o[2*l+0] = a0;
        o[2*l+1] = a1;
    }

    // 128B per thread, 8x float4 stores (out + i*32 floats is 16B-aligned)
    float4* po = (float4*)(out + (size_t)i * (2*NLEV));
    const float4* pv = (const float4*)o;
    #pragma unroll
    for (int j = 0; j < (2*NLEV)/4; ++j) po[j] = pv[j];
}

extern "C" void kernel_launch(void* const* d_in, const int* in_sizes, int n_in,
                              void* d_out, int out_size, void* d_ws, size_t ws_size,
                              hipStream_t stream)
{
    const float* x      = (const float*)d_in[0];
    const float* tables = (const float*)d_in[1];
    float* out = (float*)d_out;
    int B = in_sizes[0] / 3;

    // Replicate the reference's float32 op chain exactly on host libm:
    // b = exp((log(512)-log(16))/15); res_l = floor(16 * b**l)
    ResArr res;
    float bgrow = expf((logf(512.0f) - logf(16.0f)) / 15.0f);
    for (int l = 0; l < NLEV; ++l)
        res.r[l] = floorf(16.0f * powf(bgrow, (float)l));

    int block = 256;
    int grid = (B + block - 1) / block;
    hipLaunchKernelGGL(mrhe_kernel, dim3(grid), dim3(block), 0, stream,
                       x, tables, out, res, B);
}